// Round 1
// baseline (3620.522 us; speedup 1.0000x reference)
//
#include <hip/hip_runtime.h>
#include <hip/hip_bf16.h>

#define N_ROWS 400000
#define M_SEG  100000
#define EMB    128
#define CTXD   256
#define LATD   256
#define K1M    129   // EMB+1
#define S1M    132   // padded stride (multiple of 4)
#define K1G    385   // EMB+1+CTX
#define S1G    388   // padded stride (multiple of 4)

__device__ __forceinline__ float softplus_f(float x) {
    // log1p(exp(x)) computed stably: max(x,0) + log1p(exp(-|x|))
    return fmaxf(x, 0.f) + log1pf(expf(-fabsf(x)));
}

// ---------------------------------------------------------------------------
// Kernel 1: segment sum of [comp_emb | mole_frac] plus counts, via atomics.
// One thread per (row, col) with col in [0,130): 0..127 emb, 128 mf, 129 count.
// ---------------------------------------------------------------------------
__global__ __launch_bounds__(256) void segsum_kernel(
    const float* __restrict__ comp_emb, const float* __restrict__ mf,
    const int* __restrict__ seg, float* __restrict__ seg_sum,
    float* __restrict__ counts) {
    int i = blockIdx.x * 256 + threadIdx.x;
    if (i >= N_ROWS * 130) return;
    int row = i / 130;
    int col = i - row * 130;
    int s = seg[row];
    if (col < EMB) {
        atomicAdd(&seg_sum[(size_t)s * K1M + col], comp_emb[(size_t)row * EMB + col]);
    } else if (col == EMB) {
        atomicAdd(&seg_sum[(size_t)s * K1M + EMB], mf[row]);
    } else {
        atomicAdd(&counts[s], 1.f);
    }
}

// ---------------------------------------------------------------------------
// Kernel 2: mixture MLP. 32 pooled rows per block, 256 threads.
// Each thread computes a 16-row x 2-col tile of the 32x256 output of each layer.
// Layer inputs live in LDS; reads are float4 broadcasts (ds_read_b128).
// ---------------------------------------------------------------------------
__global__ __launch_bounds__(256) void mix_mlp_kernel(
    const float* __restrict__ seg_sum, const float* __restrict__ counts,
    const float* __restrict__ iW1, const float* __restrict__ ib1,
    const float* __restrict__ iW2, const float* __restrict__ ib2,
    float* __restrict__ ctx) {
    __shared__ float buf[32 * 256];   // layer1 a-tile uses 32*S1M (4224) floats; h uses 32*256

    const int m0  = blockIdx.x * 32;
    const int tid = threadIdx.x;
    const int rg  = tid >> 7;          // 0/1 -> row group
    const int r0  = rg * 16;
    const int c0  = (tid & 127) * 2;

    // stage pooled = seg_sum / max(counts,1) into buf[r*S1M + k]
    for (int i = tid; i < 32 * S1M; i += 256) {
        int r = i / S1M;
        int k = i - r * S1M;
        float v = 0.f;
        if (k < K1M) {
            int m = m0 + r;
            v = seg_sum[(size_t)m * K1M + k] / fmaxf(counts[m], 1.f);
        }
        buf[i] = v;
    }
    __syncthreads();

    float acc0[16], acc1[16];
    {
        float b0 = ib1[c0], b1 = ib1[c0 + 1];
        #pragma unroll
        for (int rr = 0; rr < 16; ++rr) { acc0[rr] = b0; acc1[rr] = b1; }
    }
    // layer 1: K = 129 = 32 tiles of 4 + 1 remainder
    for (int kt = 0; kt < 128; kt += 4) {
        float wa[4], wb[4];
        #pragma unroll
        for (int j = 0; j < 4; ++j) {
            wa[j] = iW1[(kt + j) * CTXD + c0];
            wb[j] = iW1[(kt + j) * CTXD + c0 + 1];
        }
        #pragma unroll
        for (int rr = 0; rr < 16; ++rr) {
            float4 a = *reinterpret_cast<const float4*>(&buf[(r0 + rr) * S1M + kt]);
            acc0[rr] = fmaf(a.x, wa[0], fmaf(a.y, wa[1], fmaf(a.z, wa[2], fmaf(a.w, wa[3], acc0[rr]))));
            acc1[rr] = fmaf(a.x, wb[0], fmaf(a.y, wb[1], fmaf(a.z, wb[2], fmaf(a.w, wb[3], acc1[rr]))));
        }
    }
    {
        float w0 = iW1[128 * CTXD + c0], w1 = iW1[128 * CTXD + c0 + 1];
        #pragma unroll
        for (int rr = 0; rr < 16; ++rr) {
            float a = buf[(r0 + rr) * S1M + 128];
            acc0[rr] = fmaf(a, w0, acc0[rr]);
            acc1[rr] = fmaf(a, w1, acc1[rr]);
        }
    }
    __syncthreads();
    // h -> LDS
    #pragma unroll
    for (int rr = 0; rr < 16; ++rr) {
        int r = r0 + rr;
        buf[r * 256 + c0]     = softplus_f(acc0[rr]);
        buf[r * 256 + c0 + 1] = softplus_f(acc1[rr]);
    }
    __syncthreads();
    // layer 2: K = 256
    {
        float b0 = ib2[c0], b1 = ib2[c0 + 1];
        #pragma unroll
        for (int rr = 0; rr < 16; ++rr) { acc0[rr] = b0; acc1[rr] = b1; }
    }
    for (int kt = 0; kt < 256; kt += 4) {
        float wa[4], wb[4];
        #pragma unroll
        for (int j = 0; j < 4; ++j) {
            wa[j] = iW2[(kt + j) * CTXD + c0];
            wb[j] = iW2[(kt + j) * CTXD + c0 + 1];
        }
        #pragma unroll
        for (int rr = 0; rr < 16; ++rr) {
            float4 a = *reinterpret_cast<const float4*>(&buf[(r0 + rr) * 256 + kt]);
            acc0[rr] = fmaf(a.x, wa[0], fmaf(a.y, wa[1], fmaf(a.z, wa[2], fmaf(a.w, wa[3], acc0[rr]))));
            acc1[rr] = fmaf(a.x, wb[0], fmaf(a.y, wb[1], fmaf(a.z, wb[2], fmaf(a.w, wb[3], acc1[rr]))));
        }
    }
    #pragma unroll
    for (int rr = 0; rr < 16; ++rr) {
        int m = m0 + r0 + rr;
        float2 v = make_float2(softplus_f(acc0[rr]), softplus_f(acc1[rr]));
        *reinterpret_cast<float2*>(&ctx[(size_t)m * CTXD + c0]) = v;
    }
}

// ---------------------------------------------------------------------------
// Kernel 3: gate MLP. 32 rows per block, 256 threads, same tiling scheme.
// Stages gate_in = [comp_emb | mf | ctx[seg]] (385 wide) in LDS.
// ---------------------------------------------------------------------------
__global__ __launch_bounds__(256) void gate_mlp_kernel(
    const float* __restrict__ comp_emb, const float* __restrict__ mf,
    const int* __restrict__ seg, const float* __restrict__ ctx,
    const float* __restrict__ gW1, const float* __restrict__ gb1,
    const float* __restrict__ gW2, const float* __restrict__ gb2,
    float* __restrict__ out) {
    __shared__ float buf[32 * S1G];   // 49.7 KB; h region (32*256) fits inside

    const int n0  = blockIdx.x * 32;
    const int tid = threadIdx.x;
    const int rg  = tid >> 7;
    const int r0  = rg * 16;
    const int c0  = (tid & 127) * 2;

    // stage gate_in rows
    for (int i = tid; i < 32 * S1G; i += 256) {
        int r = i / S1G;
        int k = i - r * S1G;
        int row = n0 + r;
        float v = 0.f;
        if (k < EMB) {
            v = comp_emb[(size_t)row * EMB + k];
        } else if (k == EMB) {
            v = mf[row];
        } else if (k < K1G) {
            v = ctx[(size_t)seg[row] * CTXD + (k - (EMB + 1))];
        }
        buf[i] = v;
    }
    __syncthreads();

    float acc0[16], acc1[16];
    {
        float b0 = gb1[c0], b1 = gb1[c0 + 1];
        #pragma unroll
        for (int rr = 0; rr < 16; ++rr) { acc0[rr] = b0; acc1[rr] = b1; }
    }
    // layer 1: K = 385 = 96 tiles of 4 + 1 remainder
    for (int kt = 0; kt < 384; kt += 4) {
        float wa[4], wb[4];
        #pragma unroll
        for (int j = 0; j < 4; ++j) {
            wa[j] = gW1[(kt + j) * LATD + c0];
            wb[j] = gW1[(kt + j) * LATD + c0 + 1];
        }
        #pragma unroll
        for (int rr = 0; rr < 16; ++rr) {
            float4 a = *reinterpret_cast<const float4*>(&buf[(r0 + rr) * S1G + kt]);
            acc0[rr] = fmaf(a.x, wa[0], fmaf(a.y, wa[1], fmaf(a.z, wa[2], fmaf(a.w, wa[3], acc0[rr]))));
            acc1[rr] = fmaf(a.x, wb[0], fmaf(a.y, wb[1], fmaf(a.z, wb[2], fmaf(a.w, wb[3], acc1[rr]))));
        }
    }
    {
        float w0 = gW1[384 * LATD + c0], w1 = gW1[384 * LATD + c0 + 1];
        #pragma unroll
        for (int rr = 0; rr < 16; ++rr) {
            float a = buf[(r0 + rr) * S1G + 384];
            acc0[rr] = fmaf(a, w0, acc0[rr]);
            acc1[rr] = fmaf(a, w1, acc1[rr]);
        }
    }
    __syncthreads();
    #pragma unroll
    for (int rr = 0; rr < 16; ++rr) {
        int r = r0 + rr;
        buf[r * 256 + c0]     = softplus_f(acc0[rr]);
        buf[r * 256 + c0 + 1] = softplus_f(acc1[rr]);
    }
    __syncthreads();
    // layer 2: K = 256
    {
        float b0 = gb2[c0], b1 = gb2[c0 + 1];
        #pragma unroll
        for (int rr = 0; rr < 16; ++rr) { acc0[rr] = b0; acc1[rr] = b1; }
    }
    for (int kt = 0; kt < 256; kt += 4) {
        float wa[4], wb[4];
        #pragma unroll
        for (int j = 0; j < 4; ++j) {
            wa[j] = gW2[(kt + j) * LATD + c0];
            wb[j] = gW2[(kt + j) * LATD + c0 + 1];
        }
        #pragma unroll
        for (int rr = 0; rr < 16; ++rr) {
            float4 a = *reinterpret_cast<const float4*>(&buf[(r0 + rr) * 256 + kt]);
            acc0[rr] = fmaf(a.x, wa[0], fmaf(a.y, wa[1], fmaf(a.z, wa[2], fmaf(a.w, wa[3], acc0[rr]))));
            acc1[rr] = fmaf(a.x, wb[0], fmaf(a.y, wb[1], fmaf(a.z, wb[2], fmaf(a.w, wb[3], acc1[rr]))));
        }
    }
    #pragma unroll
    for (int rr = 0; rr < 16; ++rr) {
        int row = n0 + r0 + rr;
        float2 v = make_float2(softplus_f(acc0[rr]), softplus_f(acc1[rr]));
        *reinterpret_cast<float2*>(&out[(size_t)row * LATD + c0]) = v;
    }
}

// ---------------------------------------------------------------------------
// Kernel 4: mole_frac pass-through into the tail of the output tuple.
// ---------------------------------------------------------------------------
__global__ __launch_bounds__(256) void mf_copy_kernel(
    const float* __restrict__ mf, float* __restrict__ out) {
    int i = blockIdx.x * 256 + threadIdx.x;
    if (i < N_ROWS) out[(size_t)N_ROWS * LATD + i] = mf[i];
}

extern "C" void kernel_launch(void* const* d_in, const int* in_sizes, int n_in,
                              void* d_out, int out_size, void* d_ws, size_t ws_size,
                              hipStream_t stream) {
    const float* comp_emb = (const float*)d_in[0];
    const float* mf       = (const float*)d_in[1];
    const int*   seg      = (const int*)d_in[2];
    const float* iW1      = (const float*)d_in[3];
    const float* ib1      = (const float*)d_in[4];
    const float* iW2      = (const float*)d_in[5];
    const float* ib2      = (const float*)d_in[6];
    const float* gW1      = (const float*)d_in[7];
    const float* gb1      = (const float*)d_in[8];
    const float* gW2      = (const float*)d_in[9];
    const float* gb2      = (const float*)d_in[10];
    float* out = (float*)d_out;

    // workspace layout (floats): seg_sum [M*129] | counts [M] | ctx [M*256]
    float* seg_sum = (float*)d_ws;
    float* counts  = seg_sum + (size_t)M_SEG * K1M;
    float* ctx     = counts + M_SEG;

    hipMemsetAsync(d_ws, 0, ((size_t)M_SEG * K1M + M_SEG) * sizeof(float), stream);

    {
        int total = N_ROWS * 130;
        segsum_kernel<<<(total + 255) / 256, 256, 0, stream>>>(comp_emb, mf, seg, seg_sum, counts);
    }
    mix_mlp_kernel<<<M_SEG / 32, 256, 0, stream>>>(seg_sum, counts, iW1, ib1, iW2, ib2, ctx);
    gate_mlp_kernel<<<N_ROWS / 32, 256, 0, stream>>>(comp_emb, mf, seg, ctx, gW1, gb1, gW2, gb2, out);
    mf_copy_kernel<<<(N_ROWS + 255) / 256, 256, 0, stream>>>(mf, out);
}